// Round 1
// baseline (339.810 us; speedup 1.0000x reference)
//
#include <hip/hip_runtime.h>
#include <hip/hip_bf16.h>

// Problem constants
// B=4, S=2048, QD=1024, NH=16, KVH=4, DH=64, WIN=256 (additive +1 mask, full softmax)

using short8 = __attribute__((ext_vector_type(8))) short;
using f32x4  = __attribute__((ext_vector_type(4))) float;

#define GLDS(g, l) __builtin_amdgcn_global_load_lds( \
    (const __attribute__((address_space(1))) void*)(g), \
    (__attribute__((address_space(3))) void*)(l), 16, 0, 0)

__device__ __forceinline__ unsigned short f2bf(float f) {
  union { float f; unsigned u; } v; v.f = f;
  unsigned r = v.u + 0x7fffu + ((v.u >> 16) & 1u);
  return (unsigned short)(r >> 16);
}

// ---------------- conversion kernels ----------------
__global__ void cvt_x_kernel(const float* __restrict__ X, unsigned short* __restrict__ Xb) {
  int i = (blockIdx.x * blockDim.x + threadIdx.x) * 4;
  float4 v = *reinterpret_cast<const float4*>(X + i);
  ushort4 o;
  o.x = f2bf(v.x); o.y = f2bf(v.y); o.z = f2bf(v.z); o.w = f2bf(v.w);
  *reinterpret_cast<ushort4*>(Xb + i) = o;
}

// src is [1024][C] row-major fp32; dst[c*1024 + r] = bf16(src[r][c])  (i.e. transpose)
__global__ void tr_cvt_kernel(const float* __restrict__ src, unsigned short* __restrict__ dst, int C) {
  int idx = blockIdx.x * blockDim.x + threadIdx.x;
  int c = idx >> 10, r = idx & 1023;
  dst[idx] = f2bf(src[(size_t)r * C + c]);
}

// ---------------- GEMM: A[M][1024] bf16 (row-major) x Bt[N][1024] bf16 -> epilogue ----------------
// 128x128 tile, 4 waves (2x2), each wave 64x64 = 4x4 frags of 16x16x32 MFMA.  m97 structure.
template<int MODE>
__global__ __launch_bounds__(256) void gemm_bt_kernel(
    const unsigned short* __restrict__ A, const unsigned short* __restrict__ Bt,
    unsigned short* __restrict__ Qo, unsigned short* __restrict__ Ko,
    unsigned short* __restrict__ Vto, float* __restrict__ Co)
{
  __shared__ __align__(16) unsigned short As[128 * 32];
  __shared__ __align__(16) unsigned short Bs[128 * 32];
  const int m0 = blockIdx.x * 128;
  const int n0 = blockIdx.y * 128;
  const int t = threadIdx.x;
  const int w = t >> 6, l = t & 63;
  const int wr = w >> 1, wc = w & 1;

  f32x4 acc[4][4] = {};

  // staging: chunk c stages 16 rows (1KB): lane -> row c*16 + l/4, col chunk (l&3)*8 elems
  const size_t aoff = (size_t)(m0 + w * 16 + (l >> 2)) * 1024 + (size_t)((l & 3) * 8);
  const size_t boff = (size_t)(n0 + w * 16 + (l >> 2)) * 1024 + (size_t)((l & 3) * 8);

  for (int kt = 0; kt < 1024; kt += 32) {
    GLDS(A  + aoff + kt,             &As[w * 512]);
    GLDS(A  + aoff + 64 * 1024 + kt, &As[(w + 4) * 512]);
    GLDS(Bt + boff + kt,             &Bs[w * 512]);
    GLDS(Bt + boff + 64 * 1024 + kt, &Bs[(w + 4) * 512]);
    __syncthreads();

    short8 af[4], bfr[4];
#pragma unroll
    for (int mi = 0; mi < 4; ++mi) {
      int row = wr * 64 + mi * 16 + (l & 15);
      af[mi] = *reinterpret_cast<const short8*>(&As[row * 32 + (l >> 4) * 8]);
    }
#pragma unroll
    for (int ni = 0; ni < 4; ++ni) {
      int row = wc * 64 + ni * 16 + (l & 15);
      bfr[ni] = *reinterpret_cast<const short8*>(&Bs[row * 32 + (l >> 4) * 8]);
    }
#pragma unroll
    for (int mi = 0; mi < 4; ++mi)
#pragma unroll
      for (int ni = 0; ni < 4; ++ni)
        acc[mi][ni] = __builtin_amdgcn_mfma_f32_16x16x32_bf16(af[mi], bfr[ni], acc[mi][ni], 0, 0, 0);
    __syncthreads();
  }

  // epilogue: C/D layout col = lane&15, row = (lane>>4)*4 + reg  (m89-verified)
#pragma unroll
  for (int mi = 0; mi < 4; ++mi)
#pragma unroll
    for (int ni = 0; ni < 4; ++ni)
#pragma unroll
      for (int r = 0; r < 4; ++r) {
        int m = m0 + wr * 64 + mi * 16 + (l >> 4) * 4 + r;
        int n = n0 + wc * 64 + ni * 16 + (l & 15);
        float val = acc[mi][ni][r];
        if (MODE == 0) {
          int b = m >> 11, s = m & 2047;
          unsigned short bv = f2bf(val);
          if (n < 1024) {                     // Q -> [B,NH,S,DH]
            int h = n >> 6, d = n & 63;
            Qo[(((size_t)(b * 16 + h) * 2048 + s) << 6) + d] = bv;
          } else if (n < 1280) {              // K -> [B,KVH,S,DH]
            int kvh = (n - 1024) >> 6, d = n & 63;
            Ko[(((size_t)(b * 4 + kvh) * 2048 + s) << 6) + d] = bv;
          } else {                            // V -> transposed [B,KVH,DH,S]
            int kvh = (n - 1280) >> 6, d = n & 63;
            Vto[((size_t)(b * 4 + kvh) * 64 + d) * 2048 + s] = bv;
          }
        } else {
          Co[((size_t)m << 10) + n] = val;    // fp32 out
        }
      }
}

// ---------------- fused flash attention ----------------
// grid (32 qblocks, 64 = B*NH). Block 256 = 4 waves; wave w owns q rows [q0+w*16, +16).
// K_lds[64][64], Vt_lds[64 dh][64 key], P_lds[64][64]; all XOR-chunk-swizzled (16B chunks).
__global__ __launch_bounds__(256) void attn_kernel(
    const unsigned short* __restrict__ Q, const unsigned short* __restrict__ Kc,
    const unsigned short* __restrict__ Vt, unsigned short* __restrict__ AO)
{
  __shared__ __align__(16) unsigned short Kl[64 * 64];
  __shared__ __align__(16) unsigned short Vl[64 * 64];
  __shared__ __align__(16) unsigned short Pl[64 * 64];

  const int t = threadIdx.x, w = t >> 6, l = t & 63;
  const int q0 = blockIdx.x * 64;
  const int hf = blockIdx.y;
  const int b = hf >> 4, h = hf & 15, kvh = h >> 2;

  const unsigned short* Qp = Q  + ((size_t)(b * 16 + h)  * 2048) * 64;
  const unsigned short* Kp = Kc + ((size_t)(b * 4 + kvh) * 2048) * 64;
  const unsigned short* Vp = Vt + ((size_t)(b * 4 + kvh) * 64) * 2048;

  // Q fragments in registers (A-frag: row = l&15, k = (l>>4)*8+e), 2 k-chunks of 32 over DH=64
  const int qr = q0 + w * 16 + (l & 15);
  short8 qf[2];
#pragma unroll
  for (int c = 0; c < 2; ++c)
    qf[c] = *reinterpret_cast<const short8*>(Qp + (size_t)qr * 64 + c * 32 + (l >> 4) * 8);

  float m_s[4], l_s[4];
  f32x4 o[4] = {};
#pragma unroll
  for (int r = 0; r < 4; ++r) { m_s[r] = -1e30f; l_s[r] = 0.f; }

  for (int kv0 = 0; kv0 < 2048; kv0 += 64) {
    __syncthreads();  // previous iteration's LDS reads complete
    // stage K and V^T tiles, swizzled via pre-swizzled global source (chunk ^= row&7)
#pragma unroll
    for (int i = 0; i < 2; ++i) {
      int c = w + i * 4;
      int row = c * 8 + (l >> 3);
      int cb = (l & 7) ^ (row & 7);
      GLDS(Kp + (size_t)(kv0 + row) * 64 + cb * 8, &Kl[c * 512]);
      GLDS(Vp + (size_t)row * 2048 + kv0 + cb * 8, &Vl[c * 512]);
    }
    __syncthreads();

    // S = Q K^T : B-frag n = key = l&15 within ni block, k = dh
    f32x4 s[4] = {};
#pragma unroll
    for (int ni = 0; ni < 4; ++ni) {
      int key = ni * 16 + (l & 15);
#pragma unroll
      for (int c = 0; c < 2; ++c) {
        int ch = (c * 4 + (l >> 4)) ^ (key & 7);
        short8 kb = *reinterpret_cast<const short8*>(&Kl[key * 64 + ch * 8]);
        s[ni] = __builtin_amdgcn_mfma_f32_16x16x32_bf16(qf[c], kb, s[ni], 0, 0, 0);
      }
    }

    // online softmax (scale 0.125, additive +1.0 window mask, full-row softmax)
    float fac[4];
#pragma unroll
    for (int r = 0; r < 4; ++r) {
      int qg = q0 + w * 16 + (l >> 4) * 4 + r;
      float vals[4], mx = -1e30f;
#pragma unroll
      for (int ni = 0; ni < 4; ++ni) {
        int key = kv0 + ni * 16 + (l & 15);
        int ad = qg > key ? qg - key : key - qg;
        float v = s[ni][r] * 0.125f + (ad <= 256 ? 1.0f : 0.0f);
        vals[ni] = v;
        mx = fmaxf(mx, v);
      }
#pragma unroll
      for (int off = 1; off < 16; off <<= 1)
        mx = fmaxf(mx, __shfl_xor(mx, off, 64));
      float mnew = fmaxf(m_s[r], mx);
      float f = __expf(m_s[r] - mnew);
      float sum = 0.f;
#pragma unroll
      for (int ni = 0; ni < 4; ++ni) {
        float p = __expf(vals[ni] - mnew);
        sum += p;
        s[ni][r] = p;
      }
#pragma unroll
      for (int off = 1; off < 16; off <<= 1)
        sum += __shfl_xor(sum, off, 64);
      l_s[r] = l_s[r] * f + sum;
      m_s[r] = mnew;
      fac[r] = f;
    }
#pragma unroll
    for (int di = 0; di < 4; ++di)
#pragma unroll
      for (int r = 0; r < 4; ++r)
        o[di][r] *= fac[r];

    // P -> LDS (bf16, swizzled); each wave touches only its own 16 rows
#pragma unroll
    for (int ni = 0; ni < 4; ++ni)
#pragma unroll
      for (int r = 0; r < 4; ++r) {
        int prow = w * 16 + (l >> 4) * 4 + r;
        int pcol = ni * 16 + (l & 15);
        int ch = (pcol >> 3) ^ (prow & 7);
        Pl[prow * 64 + ch * 8 + (pcol & 7)] = f2bf(s[ni][r]);
      }
    __syncthreads();

    // O += P V : A-frag P rows = wave's 16 q rows, B-frag V[key][dh] from Vt_lds[dh][key]
#pragma unroll
    for (int kc = 0; kc < 2; ++kc) {
      int prow = w * 16 + (l & 15);
      int pch = (kc * 4 + (l >> 4)) ^ (prow & 7);
      short8 pa = *reinterpret_cast<const short8*>(&Pl[prow * 64 + pch * 8]);
#pragma unroll
      for (int di = 0; di < 4; ++di) {
        int vrow = di * 16 + (l & 15);
        int vch = (kc * 4 + (l >> 4)) ^ (vrow & 7);
        short8 vb = *reinterpret_cast<const short8*>(&Vl[vrow * 64 + vch * 8]);
        o[di] = __builtin_amdgcn_mfma_f32_16x16x32_bf16(pa, vb, o[di], 0, 0, 0);
      }
    }
  }

  // normalize + store attn output [B,S,NH*DH] bf16
#pragma unroll
  for (int di = 0; di < 4; ++di)
#pragma unroll
    for (int r = 0; r < 4; ++r) {
      int qg = q0 + w * 16 + (l >> 4) * 4 + r;
      int d = di * 16 + (l & 15);
      float v = o[di][r] / l_s[r];
      AO[(((size_t)(b * 2048 + qg)) << 10) + h * 64 + d] = f2bf(v);
    }
}

// ---------------- launcher ----------------
extern "C" void kernel_launch(void* const* d_in, const int* in_sizes, int n_in,
                              void* d_out, int out_size, void* d_ws, size_t ws_size,
                              hipStream_t stream)
{
  const float* X  = (const float*)d_in[0];
  const float* Wq = (const float*)d_in[1];
  const float* Wk = (const float*)d_in[2];
  const float* Wv = (const float*)d_in[3];
  const float* Wo = (const float*)d_in[4];
  float* out = (float*)d_out;
  char* ws = (char*)d_ws;

  unsigned short* Xb    = (unsigned short*)(ws);                 // [8192][1024]      16 MB
  unsigned short* WqkvT = (unsigned short*)(ws + 16777216);      // [1536][1024]       3 MB
  unsigned short* WoT   = (unsigned short*)(ws + 19922944);      // [1024][1024]       2 MB
  unsigned short* Q     = (unsigned short*)(ws + 22020096);      // [B,NH,S,DH]       16 MB
  unsigned short* Kc    = (unsigned short*)(ws + 38797312);      // [B,KVH,S,DH]       4 MB
  unsigned short* Vt    = (unsigned short*)(ws + 42991616);      // [B,KVH,DH,S]       4 MB
  unsigned short* AO    = (unsigned short*)(ws + 47185920);      // [8192][1024]      16 MB

  cvt_x_kernel<<<8192, 256, 0, stream>>>(X, Xb);
  tr_cvt_kernel<<<4096, 256, 0, stream>>>(Wq, WqkvT, 1024);
  tr_cvt_kernel<<<1024, 256, 0, stream>>>(Wk, WqkvT + 1024 * 1024, 256);
  tr_cvt_kernel<<<1024, 256, 0, stream>>>(Wv, WqkvT + 1280 * 1024, 256);
  tr_cvt_kernel<<<4096, 256, 0, stream>>>(Wo, WoT, 1024);

  gemm_bt_kernel<0><<<dim3(64, 12), 256, 0, stream>>>(Xb, WqkvT, Q, Kc, Vt, nullptr);
  attn_kernel<<<dim3(32, 64), 256, 0, stream>>>(Q, Kc, Vt, AO);
  gemm_bt_kernel<1><<<dim3(64, 8), 256, 0, stream>>>(AO, WoT, nullptr, nullptr, nullptr, out);
}